// Round 2
// baseline (275.196 us; speedup 1.0000x reference)
//
#include <hip/hip_runtime.h>

// loss = sum_c (sum_spatial(input[c]) - sum_spatial(target[c]))^2 / C^2
// C=128, H=W=512 -> HW=262144 elems/channel, fp32.

#define NCH 128
#define HW (512 * 512)
#define BPC 16                         // blocks per channel -> 2048 blocks (8/CU)
#define ELEMS_PER_BLOCK (HW / BPC)     // 16384
#define NTHREADS 256

__global__ void zero_ws_kernel(float* __restrict__ ws) {
    ws[threadIdx.x] = 0.0f;
}

__global__ __launch_bounds__(NTHREADS) void chan_diff_sum_kernel(
        const float* __restrict__ inp,
        const float* __restrict__ tgt,
        float* __restrict__ ws) {
    const int bid = blockIdx.x;
    const int ch  = bid / BPC;
    const int blk = bid % BPC;
    const size_t base = (size_t)ch * HW + (size_t)blk * ELEMS_PER_BLOCK;
    const float4* __restrict__ pi = (const float4*)(inp + base);
    const float4* __restrict__ pt = (const float4*)(tgt + base);

    const int tid = threadIdx.x;
    const int NV = ELEMS_PER_BLOCK / 4;  // 4096 float4 per block
    float s0 = 0.0f, s1 = 0.0f;
    // 2 independent float4 loads per stream per iteration; 8 iterations.
    #pragma unroll 2
    for (int i = tid; i < NV; i += 2 * NTHREADS) {
        float4 a0 = pi[i];
        float4 b0 = pt[i];
        float4 a1 = pi[i + NTHREADS];
        float4 b1 = pt[i + NTHREADS];
        s0 += (a0.x - b0.x) + (a0.y - b0.y) + (a0.z - b0.z) + (a0.w - b0.w);
        s1 += (a1.x - b1.x) + (a1.y - b1.y) + (a1.z - b1.z) + (a1.w - b1.w);
    }
    float s = s0 + s1;

    // wave-64 reduce
    #pragma unroll
    for (int off = 32; off > 0; off >>= 1)
        s += __shfl_down(s, off, 64);

    __shared__ float sm[NTHREADS / 64];
    const int wave = tid >> 6;
    const int lane = tid & 63;
    if (lane == 0) sm[wave] = s;
    __syncthreads();
    if (tid == 0) {
        float t = 0.0f;
        #pragma unroll
        for (int w = 0; w < NTHREADS / 64; ++w) t += sm[w];
        atomicAdd(&ws[ch], t);
    }
}

__global__ void finalize_kernel(const float* __restrict__ ws,
                                float* __restrict__ out) {
    const int tid = threadIdx.x;  // 128 threads
    float d = ws[tid];
    float s = d * d;
    #pragma unroll
    for (int off = 32; off > 0; off >>= 1)
        s += __shfl_down(s, off, 64);
    __shared__ float sm[2];
    if ((tid & 63) == 0) sm[tid >> 6] = s;
    __syncthreads();
    if (tid == 0) out[0] = (sm[0] + sm[1]) * (1.0f / (128.0f * 128.0f));
}

extern "C" void kernel_launch(void* const* d_in, const int* in_sizes, int n_in,
                              void* d_out, int out_size, void* d_ws, size_t ws_size,
                              hipStream_t stream) {
    const float* inp = (const float*)d_in[0];
    const float* tgt = (const float*)d_in[1];
    float* out = (float*)d_out;
    float* ws  = (float*)d_ws;   // 128 floats of per-channel diff sums

    zero_ws_kernel<<<1, NCH, 0, stream>>>(ws);
    chan_diff_sum_kernel<<<NCH * BPC, NTHREADS, 0, stream>>>(inp, tgt, ws);
    finalize_kernel<<<1, NCH, 0, stream>>>(ws, out);
}